// Round 1
// baseline (136.032 us; speedup 1.0000x reference)
//
#include <hip/hip_runtime.h>
#include <math.h>

#define EPSF 1e-7f
#define MAXNF (1.0f - 1e-5f)

__device__ __forceinline__ float wsum(float v) {
#pragma unroll
  for (int off = 32; off >= 1; off >>= 1) v += __shfl_xor(v, off, 64);
  return v;
}

__device__ __forceinline__ float dot4(const float4 a, const float4 b) {
  return a.x * b.x + a.y * b.y + a.z * b.z + a.w * b.w;
}

// One mobius_add step on a 256-dim vector distributed 4 elems/lane across a
// full 64-lane wave. All lanes get the reduced sums via xor-butterfly.
__device__ __forceinline__ float4 mobius_step(const float4 x, const float4 y) {
  float px = wsum(dot4(x, x));
  float py = wsum(dot4(y, y));
  float pxy = wsum(dot4(x, y));
  float cx = 1.f + 2.f * pxy + py;
  float cy = 1.f - px;
  float inv = 1.f / fmaxf(1.f + 2.f * pxy + px * py, EPSF);
  float4 r;
  r.x = (cx * x.x + cy * y.x) * inv;
  r.y = (cx * x.y + cy * y.y) * inv;
  r.z = (cx * x.z + cy * y.z) * inv;
  r.w = (cx * x.w + cy * y.w) * inv;
  return r;
}

// Kernel 1: block = (j,k), j in [0,64), k in [0,16).
// Computes h1[a] for a = src_idx[idx_j*16 + k] and stores it at ws row j*16+k.
__global__ __launch_bounds__(256) void
k1_h1(const float* __restrict__ features, const float* __restrict__ W1,
      const float* __restrict__ b1, const int* __restrict__ src_idx,
      const int* __restrict__ to_fetch, float* __restrict__ h1) {
  const int blk = blockIdx.x;  // j*16 + k
  const int j = blk >> 4;
  const int k = blk & 15;
  const int tid = threadIdx.x;

  __shared__ float feat[16][512];   // 32 KB: 0.25-scaled neighbor feature rows
  __shared__ float trow[16][256];   // 16 KB: transformed rows
  __shared__ float srow[16];
  __shared__ int vnode[16];
  __shared__ int s_a;

  if (tid == 0) {
    int idxj = to_fetch[j] + (j << 10);
    s_a = src_idx[idxj * 16 + k];
  }
  __syncthreads();
  if (tid < 16) vnode[tid] = src_idx[s_a * 16 + tid];
  __syncthreads();

  // Stage 16 feature rows (512 floats each) scaled by K^-0.5 = 0.25.
#pragma unroll
  for (int it = 0; it < 8; ++it) {
    int t = (it << 8) + tid;   // 0..2047 float4 slots
    int r = t >> 7;            // 128 float4 per row
    int c = (t & 127) << 2;
    const float4 f =
        *reinterpret_cast<const float4*>(features + (size_t)vnode[r] * 512 + c);
    feat[r][c + 0] = 0.25f * f.x;
    feat[r][c + 1] = 0.25f * f.y;
    feat[r][c + 2] = 0.25f * f.z;
    feat[r][c + 3] = 0.25f * f.w;
  }
  __syncthreads();

  // GEMM: mx[r][n] = sum_kk feat[r][kk] * W1[kk][n]; thread tid owns column n.
  float acc[16];
#pragma unroll
  for (int r = 0; r < 16; ++r) acc[r] = 0.f;
  for (int kk = 0; kk < 512; kk += 4) {
    float w0 = W1[(kk + 0) * 256 + tid];
    float w1 = W1[(kk + 1) * 256 + tid];
    float w2 = W1[(kk + 2) * 256 + tid];
    float w3 = W1[(kk + 3) * 256 + tid];
#pragma unroll
    for (int r = 0; r < 16; ++r) {
      const float4 f = *reinterpret_cast<const float4*>(&feat[r][kk]);
      acc[r] = fmaf(f.x, w0, acc[r]);
      acc[r] = fmaf(f.y, w1, acc[r]);
      acc[r] = fmaf(f.z, w2, acc[r]);
      acc[r] = fmaf(f.w, w3, acc[r]);
    }
  }
#pragma unroll
  for (int r = 0; r < 16; ++r) trow[r][tid] = acc[r];
  __syncthreads();

  // Per-row mobius_matvec scale: tanh(mxn/xn*atanh(xn))/mxn.
  {
    const int w = tid >> 6, lane = tid & 63;
#pragma unroll
    for (int rr = 0; rr < 4; ++rr) {
      const int r = (w << 2) + rr;
      float xs2 = 0.f, ms2 = 0.f;
#pragma unroll
      for (int c = 0; c < 512; c += 64) {
        float v = feat[r][c + lane];
        xs2 = fmaf(v, v, xs2);
      }
#pragma unroll
      for (int c = 0; c < 256; c += 64) {
        float v = trow[r][c + lane];
        ms2 = fmaf(v, v, ms2);
      }
      xs2 = wsum(xs2);
      ms2 = wsum(ms2);
      if (lane == 0) {
        float xn = fminf(fmaxf(sqrtf(xs2), EPSF), MAXNF);
        float mxn = fmaxf(sqrtf(ms2), EPSF);
        srow[r] = tanhf(mxn / xn * atanhf(xn)) / mxn;
      }
    }
  }
  __syncthreads();
#pragma unroll
  for (int r = 0; r < 16; ++r) trow[r][tid] = acc[r] * srow[r];
  __syncthreads();

  // Chained mobius_add over the 16 transformed rows, on wave 0 only.
  if (tid < 64) {
    const int l4 = tid << 2;
    float4 x = *reinterpret_cast<const float4*>(&trow[0][l4]);
#pragma unroll 1
    for (int kk = 1; kk < 16; ++kk) {
      const float4 y = *reinterpret_cast<const float4*>(&trow[kk][l4]);
      x = mobius_step(x, y);
    }
    // rst *= 0.25
    x.x *= 0.25f; x.y *= 0.25f; x.z *= 0.25f; x.w *= 0.25f;
    // mobius_add(rst, b1)
    {
      const float4 b = *reinterpret_cast<const float4*>(b1 + l4);
      x = mobius_step(x, b);
    }
    // expmap0(relu(logmap0(x)))
    float pn = wsum(dot4(x, x));
    float yn = fminf(fmaxf(sqrtf(pn), EPSF), MAXNF);
    float s = atanhf(yn) / yn;
    float4 v;
    v.x = fmaxf(s * x.x, 0.f);
    v.y = fmaxf(s * x.y, 0.f);
    v.z = fmaxf(s * x.z, 0.f);
    v.w = fmaxf(s * x.w, 0.f);
    float pv = wsum(dot4(v, v));
    float vn = fmaxf(sqrtf(pv), EPSF);
    float s2 = tanhf(vn) / vn;
    float4 h;
    h.x = s2 * v.x;
    h.y = s2 * v.y;
    h.z = s2 * v.z;
    h.w = s2 * v.w;
    *reinterpret_cast<float4*>(h1 + (size_t)blk * 256 + l4) = h;
  }
}

// Kernel 2: one wave per output row j. Layer-2 aggregate+matvec+nonlinearity,
// then layer-3 classifier.
__global__ __launch_bounds__(64) void
k2_out(const float* __restrict__ h1, const float* __restrict__ W2,
       const float* __restrict__ b2, const float* __restrict__ Wl,
       const float* __restrict__ bl, float* __restrict__ out) {
  const int j = blockIdx.x;
  const int l = threadIdx.x;
  const int l4 = l << 2;
  __shared__ float xs[256];

  const float* base = h1 + (size_t)j * 16 * 256;
  float4 x = *reinterpret_cast<const float4*>(base + l4);
  x.x *= 0.25f; x.y *= 0.25f; x.z *= 0.25f; x.w *= 0.25f;
#pragma unroll 1
  for (int kk = 1; kk < 16; ++kk) {
    float4 y = *reinterpret_cast<const float4*>(base + kk * 256 + l4);
    y.x *= 0.25f; y.y *= 0.25f; y.z *= 0.25f; y.w *= 0.25f;
    x = mobius_step(x, y);
  }

  // mobius_matvec(x, W2): mx[n] = sum_d x[d] * W2[d][n]
  *reinterpret_cast<float4*>(&xs[l4]) = x;
  __syncthreads();
  float4 mx = make_float4(0.f, 0.f, 0.f, 0.f);
  for (int d = 0; d < 256; ++d) {
    const float xd = xs[d];
    const float4 w = *reinterpret_cast<const float4*>(W2 + d * 256 + l4);
    mx.x = fmaf(xd, w.x, mx.x);
    mx.y = fmaf(xd, w.y, mx.y);
    mx.z = fmaf(xd, w.z, mx.z);
    mx.w = fmaf(xd, w.w, mx.w);
  }
  {
    float px = wsum(dot4(x, x));
    float pm = wsum(dot4(mx, mx));
    float xn = fminf(fmaxf(sqrtf(px), EPSF), MAXNF);
    float mxn = fmaxf(sqrtf(pm), EPSF);
    float s = tanhf(mxn / xn * atanhf(xn)) / mxn;
    s *= 0.25f;  // rst * norm
    x.x = s * mx.x; x.y = s * mx.y; x.z = s * mx.z; x.w = s * mx.w;
  }
  // mobius_add(x, b2)
  {
    const float4 b = *reinterpret_cast<const float4*>(b2 + l4);
    x = mobius_step(x, b);
  }
  // expmap0(relu(logmap0(x)))
  float pn = wsum(dot4(x, x));
  float yn = fminf(fmaxf(sqrtf(pn), EPSF), MAXNF);
  float s = atanhf(yn) / yn;
  float4 v;
  v.x = fmaxf(s * x.x, 0.f);
  v.y = fmaxf(s * x.y, 0.f);
  v.z = fmaxf(s * x.z, 0.f);
  v.w = fmaxf(s * x.w, 0.f);
  float pv = wsum(dot4(v, v));
  float vn = fmaxf(sqrtf(pv), EPSF);
  float s2 = tanhf(vn) / vn;
  float4 h;
  h.x = s2 * v.x; h.y = s2 * v.y; h.z = s2 * v.z; h.w = s2 * v.w;

  // Layer 3: mx2[o] = sum_d h[d] * Wl[o][d], o = lane.
  __syncthreads();
  *reinterpret_cast<float4*>(&xs[l4]) = h;
  __syncthreads();
  float m = 0.f;
  for (int d = 0; d < 256; d += 4) {
    const float4 w = *reinterpret_cast<const float4*>(Wl + (size_t)l * 256 + d);
    m = fmaf(w.x, xs[d + 0], m);
    m = fmaf(w.y, xs[d + 1], m);
    m = fmaf(w.z, xs[d + 2], m);
    m = fmaf(w.w, xs[d + 3], m);
  }
  float ph = wsum(dot4(h, h));
  float pmm = wsum(m * m);
  float hn = fminf(fmaxf(sqrtf(ph), EPSF), MAXNF);
  float mn = fmaxf(sqrtf(pmm), EPSF);
  float sc = tanhf(mn / hn * atanhf(hn)) / mn;
  float mo = sc * m;
  // mobius_add(mo, bl) on the 64-dim output row (1 elem/lane).
  float bo = bl[l];
  float pxx = wsum(mo * mo);
  float pbb = wsum(bo * bo);
  float pxb = wsum(mo * bo);
  float cx = 1.f + 2.f * pxb + pbb;
  float cy = 1.f - pxx;
  float inv = 1.f / fmaxf(1.f + 2.f * pxb + pxx * pbb, EPSF);
  out[j * 64 + l] = (cx * mo + cy * bo) * inv;
}

extern "C" void kernel_launch(void* const* d_in, const int* in_sizes, int n_in,
                              void* d_out, int out_size, void* d_ws,
                              size_t ws_size, hipStream_t stream) {
  const float* features = (const float*)d_in[0];
  const float* W1 = (const float*)d_in[1];
  const float* b1 = (const float*)d_in[2];
  const float* W2 = (const float*)d_in[3];
  const float* b2 = (const float*)d_in[4];
  const float* Wl = (const float*)d_in[5];
  const float* bl = (const float*)d_in[6];
  const int* src_idx = (const int*)d_in[7];
  const int* to_fetch = (const int*)d_in[8];
  float* out = (float*)d_out;
  float* h1 = (float*)d_ws;  // 1024 * 256 floats = 1 MB scratch

  k1_h1<<<1024, 256, 0, stream>>>(features, W1, b1, src_idx, to_fetch, h1);
  k2_out<<<64, 64, 0, stream>>>(h1, W2, b2, Wl, bl, out);
}